// Round 2
// baseline (717.111 us; speedup 1.0000x reference)
//
#include <hip/hip_runtime.h>
#include <stdint.h>

#define T_ 512
#define K_ 256
#define NB 16
#define L2E 1.4426950408889634f
#define LN2 0.6931471805599453f

typedef __attribute__((ext_vector_type(8))) short short8;
typedef __attribute__((ext_vector_type(4))) float f32x4;

__device__ __forceinline__ float fexp2(float x) {
#if __has_builtin(__builtin_amdgcn_exp2f)
  return __builtin_amdgcn_exp2f(x);
#else
  return exp2f(x);
#endif
}
__device__ __forceinline__ float flog2(float x) {
#if __has_builtin(__builtin_amdgcn_logf)
  return __builtin_amdgcn_logf(x);
#else
  return log2f(x);
#endif
}

__device__ __forceinline__ unsigned short f2bf(float f) {
  union { float f; uint32_t u; } v; v.f = f;
  uint32_t r = v.u + 0x7fffu + ((v.u >> 16) & 1u);
  return (unsigned short)(r >> 16);
}

__device__ __forceinline__ float sel8(float4 A, float4 B, int r) {
  float v = A.x;
  v = (r == 1) ? A.y : v;
  v = (r == 2) ? A.z : v;
  v = (r == 3) ? A.w : v;
  v = (r == 4) ? B.x : v;
  v = (r == 5) ? B.y : v;
  v = (r == 6) ? B.z : v;
  v = (r == 7) ? B.w : v;
  return v;
}
__device__ __forceinline__ float min4(float4 a) {
  return fminf(fminf(a.x, a.y), fminf(a.z, a.w));
}

// barrier with LDS-only drain: global loads (vmcnt) stay in flight
#define BAR() do { \
  asm volatile("s_waitcnt lgkmcnt(0)" ::: "memory"); \
  __builtin_amdgcn_s_barrier(); \
  asm volatile("" ::: "memory"); \
} while (0)

// Efrag[((mt*8+kb)*64+lane)*8+e] = bf16(exp(trans[k][j])), A-frag layout for
// mfma_f32_16x16x32_bf16: A[row=j=mt*16+(lane&15)][k=kb*32+(lane>>4)*8+e]
__global__ void prep_E(const float* __restrict__ trans, unsigned short* __restrict__ Efrag) {
  int idx = blockIdx.x * 256 + threadIdx.x;  // 0..65535
  int e = idx & 7;
  int ln = (idx >> 3) & 63;
  int kb = (idx >> 9) & 7;
  int mt = idx >> 12;
  int j = mt * 16 + (ln & 15);
  int k = kb * 32 + ((ln >> 4) << 3) + e;
  Efrag[idx] = f2bf(__expf(trans[k * K_ + j]));
}

__global__ __launch_bounds__(512, 2) void crf_fwd(
    const float* __restrict__ yp, const float* __restrict__ trans,
    const int* __restrict__ ytrue, const unsigned short* __restrict__ Efrag,
    float* __restrict__ out) {
  const int b0 = blockIdx.x * NB;
  const int tid = threadIdx.x;
  const int wv = tid >> 6, lane = tid & 63;
  const int c = lane & 15;          // batch column in GEMM layout
  const int g = lane >> 4;          // k-group / row-group
  const int cs3 = (c & 7) << 3;     // swizzle for ushort-element LDS (16B units)
  const int cs2 = (c & 7) << 2;     // swizzle for float-element LDS
  const int mt0 = wv * 2;           // this wave's first tag-tile (tags mt0*16..)

  __shared__ unsigned short Wl[2 * NB * K_];   // 16 KB  w (bf16), [buf][batch][tag]
  __shared__ float XBl[2 * NB * K_];           // 32 KB  x,      [buf][batch][tag]
  __shared__ int ysl[NB * T_];                 // 32 KB
  __shared__ float Mpartl[2 * 8 * NB];         // per-wave partial maxes
  __shared__ int mflagl[2 * NB];
  __shared__ float Spart[8 * NB];
  __shared__ float Ppart[NB];
  __shared__ float Tpart[NB];

  // ---- ys -> LDS ----
  {
    const int4* src = (const int4*)(ytrue + b0 * T_);
    int4* dst = (int4*)ysl;
    #pragma unroll
    for (int i = 0; i < 4; ++i) dst[tid + 512 * i] = src[tid + 512 * i];
  }

  // ---- E fragments -> registers (64 VGPR) ----
  short8 Ef[2][8];
  {
    const uint4* ep = (const uint4*)Efrag;
    #pragma unroll
    for (int m = 0; m < 2; ++m)
      #pragma unroll
      for (int kb = 0; kb < 8; ++kb)
        Ef[m][kb] = __builtin_bit_cast(short8, ep[((mt0 + m) * 8 + kb) * 64 + lane]);
  }

  // ---- loader role setup ----
  const int rb = tid >> 5;             // batch row this thread loads
  const int cb = (tid & 31) * 8;       // col base (8 floats)
  const float* xbase = yp + ((size_t)(b0 + rb) * T_) * K_ + cb;
  const int xwsw = (cb ^ ((rb & 7) << 2)) + rb * K_;  // swizzled write base (buf 0)

  float4 xw0, xw1;   // holds x(t+1) to be written at body t
  float4 xl0, xl1;   // loads in flight: x(t+2)
  float pacc = 0.f, tacc = 0.f;
  int mprev_l = 0;

  // ---- init: t=0 and t=1 ----
  {
    float4 a0 = *(const float4*)(xbase + 0);
    float4 a1 = *(const float4*)(xbase + 4);
    float4 e0 = *(const float4*)(xbase + K_);
    float4 e1 = *(const float4*)(xbase + K_ + 4);
    float mn0 = fminf(min4(a0), min4(a1));
    float mn1 = fminf(min4(e0), min4(e1));
    unsigned long long bl0 = __ballot(mn0 > -1000000.0f);
    unsigned long long bl1 = __ballot(mn1 > -1000000.0f);
    uint32_t h0 = (tid & 32) ? (uint32_t)(bl0 >> 32) : (uint32_t)bl0;
    uint32_t h1 = (tid & 32) ? (uint32_t)(bl1 >> 32) : (uint32_t)bl1;
    int m0 = (h0 == 0xffffffffu), m1 = (h1 == 0xffffffffu);
    *(float4*)(&XBl[xwsw]) = a0;
    *(float4*)(&XBl[xwsw ^ 4]) = a1;
    *(float4*)(&XBl[4096 + xwsw]) = e0;
    *(float4*)(&XBl[4096 + (xwsw ^ 4)]) = e1;
    if ((tid & 31) == 0) { mflagl[rb] = m0; mflagl[NB + rb] = m1; mprev_l = m0; }
    int y0 = ytrue[(b0 + rb) * T_ + 0];
    int y1 = ytrue[(b0 + rb) * T_ + 1];
    int r0 = y0 - cb, r1 = y1 - cb;
    if (m0 && (unsigned)r0 < 8u) pacc += sel8(a0, a1, r0);
    if (m1 && (unsigned)r1 < 8u) pacc += sel8(e0, e1, r1);
  }
  __syncthreads();

  // beta(0) from XB[0]
  float bet[8];
  const int tb0 = mt0 * 16 + g * 4, tb1 = tb0 + 16;
  {
    float4 x0 = *(const float4*)(&XBl[c * K_ + (tb0 ^ cs2)]);
    float4 x1 = *(const float4*)(&XBl[c * K_ + (tb1 ^ cs2)]);
    int mk = mflagl[c];
    bet[0] = mk ? x0.x * L2E : 0.f;
    bet[1] = mk ? x0.y * L2E : 0.f;
    bet[2] = mk ? x0.z * L2E : 0.f;
    bet[3] = mk ? x0.w * L2E : 0.f;
    bet[4] = mk ? x1.x * L2E : 0.f;
    bet[5] = mk ? x1.y * L2E : 0.f;
    bet[6] = mk ? x1.z * L2E : 0.f;
    bet[7] = mk ? x1.w * L2E : 0.f;
  }
  // Mpart for beta(0) -> buf 0
  {
    float pm = bet[0];
    #pragma unroll
    for (int i = 1; i < 8; ++i) pm = fmaxf(pm, bet[i]);
    pm = fmaxf(pm, __shfl_xor(pm, 16, 64));
    pm = fmaxf(pm, __shfl_xor(pm, 32, 64));
    if (lane < 16) Mpartl[wv * NB + c] = pm;
  }
  // start x(2) loads
  xw0 = *(const float4*)(xbase + 2 * K_);
  xw1 = *(const float4*)(xbase + 2 * K_ + 4);
  float Mcur = 32.0f;  // safe overestimate of max beta(0); only affects scaling

  #pragma unroll 1
  for (int t = 1; t < T_; ++t) {
    const int wb = (t & 1) * 4096;  // current W / XB buffer (element offset)
    // issue x(t+2) loads
    if (t <= 509) {
      xl0 = *(const float4*)(xbase + (size_t)(t + 2) * K_);
      xl1 = *(const float4*)(xbase + (size_t)(t + 2) * K_ + 4);
    }
    // ---- w-phase: w = 2^(beta - Mcur), write bf16 to W[t&1] ----
    {
      ushort4 p0, p1;
      p0.x = f2bf(fexp2(bet[0] - Mcur));
      p0.y = f2bf(fexp2(bet[1] - Mcur));
      p0.z = f2bf(fexp2(bet[2] - Mcur));
      p0.w = f2bf(fexp2(bet[3] - Mcur));
      p1.x = f2bf(fexp2(bet[4] - Mcur));
      p1.y = f2bf(fexp2(bet[5] - Mcur));
      p1.z = f2bf(fexp2(bet[6] - Mcur));
      p1.w = f2bf(fexp2(bet[7] - Mcur));
      *(ushort4*)(&Wl[wb + c * K_ + (tb0 ^ cs3)]) = p0;
      *(ushort4*)(&Wl[wb + c * K_ + (tb1 ^ cs3)]) = p1;
    }
    BAR();
    // ---- combine next step's stale max (off critical path) ----
    float Mn;
    {
      const int mb = ((t - 1) & 1) * 128;
      Mn = Mpartl[mb + c];
      #pragma unroll
      for (int w = 1; w < 8; ++w) Mn = fmaxf(Mn, Mpartl[mb + w * NB + c]);
    }
    // ---- GEMM: S[tag][batch] = sum_i w[batch][i] * E[i][tag] ----
    f32x4 ac0 = {0.f, 0.f, 0.f, 0.f}, ac1 = {0.f, 0.f, 0.f, 0.f};
    #pragma unroll
    for (int kb = 0; kb < 8; ++kb) {
      short8 bf = __builtin_bit_cast(short8,
          *(const uint4*)(&Wl[wb + c * K_ + ((kb * 32 + g * 8) ^ cs3)]));
      ac0 = __builtin_amdgcn_mfma_f32_16x16x32_bf16(Ef[0][kb], bf, ac0, 0, 0, 0);
      ac1 = __builtin_amdgcn_mfma_f32_16x16x32_bf16(Ef[1][kb], bf, ac1, 0, 0, 0);
    }
    // ---- beta update ----
    {
      float4 x0 = *(const float4*)(&XBl[wb + c * K_ + (tb0 ^ cs2)]);
      float4 x1 = *(const float4*)(&XBl[wb + c * K_ + (tb1 ^ cs2)]);
      int mk = mflagl[(t & 1) * NB + c];
      float n0 = Mcur + flog2(ac0[0]) + x0.x * L2E;
      float n1 = Mcur + flog2(ac0[1]) + x0.y * L2E;
      float n2 = Mcur + flog2(ac0[2]) + x0.z * L2E;
      float n3 = Mcur + flog2(ac0[3]) + x0.w * L2E;
      float n4 = Mcur + flog2(ac1[0]) + x1.x * L2E;
      float n5 = Mcur + flog2(ac1[1]) + x1.y * L2E;
      float n6 = Mcur + flog2(ac1[2]) + x1.z * L2E;
      float n7 = Mcur + flog2(ac1[3]) + x1.w * L2E;
      bet[0] = mk ? n0 : bet[0];
      bet[1] = mk ? n1 : bet[1];
      bet[2] = mk ? n2 : bet[2];
      bet[3] = mk ? n3 : bet[3];
      bet[4] = mk ? n4 : bet[4];
      bet[5] = mk ? n5 : bet[5];
      bet[6] = mk ? n6 : bet[6];
      bet[7] = mk ? n7 : bet[7];
    }
    Mcur = Mn;
    // ---- per-wave partial max of beta(t) -> Mpart[t&1] ----
    {
      float pm = bet[0];
      #pragma unroll
      for (int i = 1; i < 8; ++i) pm = fmaxf(pm, bet[i]);
      pm = fmaxf(pm, __shfl_xor(pm, 16, 64));
      pm = fmaxf(pm, __shfl_xor(pm, 32, 64));
      if (lane < 16) Mpartl[(t & 1) * 128 + wv * NB + c] = pm;
    }
    // ---- loader tail: write x(t+1), flag, point, trans ----
    {
      if (t <= 510) {
        const int xi = ((t + 1) & 1) * 4096 + xwsw;
        *(float4*)(&XBl[xi]) = xw0;
        *(float4*)(&XBl[xi ^ 4]) = xw1;
        float mn = fminf(min4(xw0), min4(xw1));
        unsigned long long bl = __ballot(mn > -1000000.0f);
        uint32_t h = (tid & 32) ? (uint32_t)(bl >> 32) : (uint32_t)bl;
        int mflg = (h == 0xffffffffu);
        if ((tid & 31) == 0) mflagl[((t + 1) & 1) * NB + rb] = mflg;
        int y = ysl[rb * T_ + t + 1];
        int r = y - cb;
        if (mflg && (unsigned)r < 8u) pacc += sel8(xw0, xw1, r);
      }
      if ((tid & 31) == 0) {
        int ya = ysl[rb * T_ + t - 1];
        int yb = ysl[rb * T_ + t];
        float tl = trans[ya * K_ + yb];
        int mc = mflagl[(t & 1) * NB + rb];
        if (mprev_l && mc) tacc += tl;
        mprev_l = mc;
      }
      xw0 = xl0; xw1 = xl1;
    }
  }

  // ---- final: exact logsumexp of beta(511) + score assembly ----
  __syncthreads();
  {
    float pm = bet[0];
    #pragma unroll
    for (int i = 1; i < 8; ++i) pm = fmaxf(pm, bet[i]);
    pm = fmaxf(pm, __shfl_xor(pm, 16, 64));
    pm = fmaxf(pm, __shfl_xor(pm, 32, 64));
    if (lane < 16) Mpartl[wv * NB + c] = pm;
  }
  __syncthreads();
  float Mf = Mpartl[c];
  #pragma unroll
  for (int w = 1; w < 8; ++w) Mf = fmaxf(Mf, Mpartl[w * NB + c]);
  {
    float e = 0.f;
    #pragma unroll
    for (int i = 0; i < 8; ++i) e += fexp2(bet[i] - Mf);
    e += __shfl_xor(e, 16, 64);
    e += __shfl_xor(e, 32, 64);
    if (lane < 16) Spart[wv * NB + c] = e;
  }
  {
    float p = pacc;
    #pragma unroll
    for (int off = 1; off < 32; off <<= 1) p += __shfl_xor(p, off, 32);
    if ((tid & 31) == 0) { Ppart[rb] = p; Tpart[rb] = tacc; }
  }
  __syncthreads();
  if (tid < NB) {
    float S = 0.f;
    #pragma unroll
    for (int w = 0; w < 8; ++w) S += Spart[w * NB + tid];
    out[b0 + tid] = LN2 * (Mf + flog2(S)) - (Ppart[tid] + Tpart[tid]);
  }
}

extern "C" void kernel_launch(void* const* d_in, const int* in_sizes, int n_in,
                              void* d_out, int out_size, void* d_ws, size_t ws_size,
                              hipStream_t stream) {
  const float* yp = (const float*)d_in[0];
  const float* trans = (const float*)d_in[1];
  const int* ytrue = (const int*)d_in[2];
  float* out = (float*)d_out;
  unsigned short* Efrag = (unsigned short*)d_ws;  // 128 KB

  prep_E<<<dim3(256), dim3(256), 0, stream>>>(trans, Efrag);
  crf_fwd<<<dim3(8), dim3(512), 0, stream>>>(yp, trans, ytrue, Efrag, out);
}

// Round 3
// 617.396 us; speedup vs baseline: 1.1615x; 1.1615x over previous
//
#include <hip/hip_runtime.h>
#include <stdint.h>

#define T_ 512
#define K_ 256
#define NB 16
#define L2E 1.4426950408889634f
#define LN2 0.6931471805599453f

typedef __attribute__((ext_vector_type(8))) short short8;
typedef __attribute__((ext_vector_type(4))) float f32x4;

__device__ __forceinline__ float fexp2(float x) {
#if __has_builtin(__builtin_amdgcn_exp2f)
  return __builtin_amdgcn_exp2f(x);
#else
  return exp2f(x);
#endif
}
__device__ __forceinline__ float flog2(float x) {
#if __has_builtin(__builtin_amdgcn_logf)
  return __builtin_amdgcn_logf(x);
#else
  return log2f(x);
#endif
}

__device__ __forceinline__ unsigned short f2bf(float f) {
  union { float f; uint32_t u; } v; v.f = f;
  uint32_t r = v.u + 0x7fffu + ((v.u >> 16) & 1u);
  return (unsigned short)(r >> 16);
}

// lgkm-only barrier: global loads stay in flight across it
#define BAR() do { \
  asm volatile("s_waitcnt lgkmcnt(0)" ::: "memory"); \
  __builtin_amdgcn_s_barrier(); \
  asm volatile("" ::: "memory"); \
} while (0)

// Efrag[((mt*8+kb)*64+lane)*8+e] = bf16(exp(trans[k][j])), A-frag layout for
// mfma_f32_16x16x32_bf16: A[row=j=mt*16+(lane&15)][k=kb*32+(lane>>4)*8+e]
// (byte-identical to round 2 — proven correct)
__global__ void prep_E(const float* __restrict__ trans, unsigned short* __restrict__ Efrag) {
  int idx = blockIdx.x * 256 + threadIdx.x;  // 0..65535
  int e = idx & 7;
  int ln = (idx >> 3) & 63;
  int kb = (idx >> 9) & 7;
  int mt = idx >> 12;
  int j = mt * 16 + (ln & 15);
  int k = kb * 32 + ((ln >> 4) << 3) + e;
  Efrag[idx] = f2bf(__expf(trans[k * K_ + j]));
}

// masks[t*128 + b] = all(y_pred[b][t][:] > -1e6)
__global__ void aux_mask(const float* __restrict__ yp, unsigned char* __restrict__ masks) {
  int item = blockIdx.x * 4 + (threadIdx.x >> 6);  // b*512 + t
  int lane = threadIdx.x & 63;
  const float4 v = *(const float4*)(yp + (size_t)item * K_ + lane * 4);
  float mn = fminf(fminf(v.x, v.y), fminf(v.z, v.w));
  unsigned long long bl = __ballot(mn > -1000000.0f);
  if (lane == 0) {
    int b = item >> 9, t = item & 511;
    masks[t * 128 + b] = (bl == ~0ull) ? 1 : 0;
  }
}

// score[b] = point_score + trans_score (one wave per batch)
__global__ void aux_score(const float* __restrict__ yp, const float* __restrict__ trans,
                          const int* __restrict__ ytrue, const unsigned char* __restrict__ masks,
                          float* __restrict__ score) {
  int b = blockIdx.x;
  int lane = threadIdx.x;  // 0..63
  float s = 0.f;
  #pragma unroll
  for (int k = 0; k < 8; ++k) {
    int t = lane + 64 * k;
    int y = ytrue[b * T_ + t];
    int m = masks[t * 128 + b];
    float x = yp[((size_t)b * T_ + t) * K_ + y];
    if (m) s += x;
    if (t >= 1) {
      int ym = ytrue[b * T_ + t - 1];
      int mm = masks[(t - 1) * 128 + b];
      if (m && mm) s += trans[ym * K_ + y];
    }
  }
  #pragma unroll
  for (int off = 32; off; off >>= 1) s += __shfl_xor(s, off, 64);
  if (lane == 0) score[b] = s;
}

__global__ __launch_bounds__(256, 1) void crf_scan(
    const float* __restrict__ yp, const unsigned short* __restrict__ Efrag,
    const unsigned char* __restrict__ masks, const float* __restrict__ score,
    float* __restrict__ out) {
  const int b0 = blockIdx.x * NB;
  const int tid = threadIdx.x;
  const int wv = tid >> 6, lane = tid & 63;
  const int c = lane & 15;   // batch column
  const int g = lane >> 4;   // k-group / row-group
  const int swz = (c & 7) << 3;  // XOR swizzle in ushort elements (16B granules)

  __shared__ unsigned short Wl[2][NB * K_];  // 16 KB, [buf][batch][tag]
  __shared__ unsigned char mkl[T_ * NB];     // 8 KB
  __shared__ unsigned int Mpart[4 * NB];     // per-wave partial max bits
  __shared__ float Spart[4 * NB];

  // ---- E fragments -> registers (128 VGPR): wave wv owns M-tiles wv*4..wv*4+3
  short8 Ef[4][8];
  {
    const uint4* ep = (const uint4*)Efrag;
    #pragma unroll
    for (int m = 0; m < 4; ++m)
      #pragma unroll
      for (int kb = 0; kb < 8; ++kb)
        Ef[m][kb] = __builtin_bit_cast(short8, ep[((wv * 4 + m) * 8 + kb) * 64 + lane]);
  }

  // ---- mask table -> LDS: mkl[t*16 + c] for columns b0..b0+15
  {
    uint4* dst = (uint4*)mkl;
    #pragma unroll
    for (int i = 0; i < 2; ++i) {
      int row = tid + 256 * i;
      dst[row] = *(const uint4*)(masks + row * 128 + b0);
    }
  }

  const float* xb = yp + (size_t)(b0 + c) * T_ * K_;
  int tb[4];
  #pragma unroll
  for (int m = 0; m < 4; ++m) tb[m] = wv * 64 + m * 16 + g * 4;

  float4 x0[4], xA[4], xB[4];
  #pragma unroll
  for (int m = 0; m < 4; ++m) x0[m] = *(const float4*)(xb + tb[m]);
  #pragma unroll
  for (int m = 0; m < 4; ++m) xA[m] = *(const float4*)(xb + K_ + tb[m]);
  #pragma unroll
  for (int m = 0; m < 4; ++m) xB[m] = *(const float4*)(xb + 2 * K_ + tb[m]);

  __syncthreads();  // mkl ready

  // ---- alpha(0), linear domain: mask0 ? exp(x0) : 1
  float a[16];
  {
    int mk0 = mkl[c];
    #pragma unroll
    for (int m = 0; m < 4; ++m) {
      a[4 * m + 0] = mk0 ? fexp2(x0[m].x * L2E) : 1.0f;
      a[4 * m + 1] = mk0 ? fexp2(x0[m].y * L2E) : 1.0f;
      a[4 * m + 2] = mk0 ? fexp2(x0[m].z * L2E) : 1.0f;
      a[4 * m + 3] = mk0 ? fexp2(x0[m].w * L2E) : 1.0f;
    }
  }
  // exl = exp(x(1))
  float exl[16];
  #pragma unroll
  for (int m = 0; m < 4; ++m) {
    exl[4 * m + 0] = fexp2(xA[m].x * L2E);
    exl[4 * m + 1] = fexp2(xA[m].y * L2E);
    exl[4 * m + 2] = fexp2(xA[m].z * L2E);
    exl[4 * m + 3] = fexp2(xA[m].w * L2E);
  }
  int acc = 0;               // accumulated log2 of applied scales
  int mkc = mkl[NB + c];     // mask(1)

  #pragma unroll 1
  for (int t = 1; t < T_; ++t) {
    // ---- pack alpha -> bf16 (truncate via v_perm), write W[t&1] ----
    {
      unsigned short* wrow = &Wl[t & 1][c * K_];
      #pragma unroll
      for (int m = 0; m < 4; ++m) {
        uint32_t p0 = __builtin_amdgcn_perm(
            __builtin_bit_cast(uint32_t, a[4 * m + 1]),
            __builtin_bit_cast(uint32_t, a[4 * m + 0]), 0x07060302u);
        uint32_t p1 = __builtin_amdgcn_perm(
            __builtin_bit_cast(uint32_t, a[4 * m + 3]),
            __builtin_bit_cast(uint32_t, a[4 * m + 2]), 0x07060302u);
        uint2 pp; pp.x = p0; pp.y = p1;
        *(uint2*)(&wrow[tb[m] ^ swz]) = pp;
      }
    }
    // ---- issue x(t+2) prefetch (stays in flight across BAR) ----
    {
      int tt = (t + 2 < T_) ? t + 2 : T_ - 1;
      if (t & 1) {
        #pragma unroll
        for (int m = 0; m < 4; ++m) xA[m] = *(const float4*)(xb + (size_t)tt * K_ + tb[m]);
      } else {
        #pragma unroll
        for (int m = 0; m < 4; ++m) xB[m] = *(const float4*)(xb + (size_t)tt * K_ + tb[m]);
      }
    }
    BAR();
    // ---- rescale factor every 4th step (reads Mpart written at t-1) ----
    float sf = 1.0f;
    if ((t & 3) == 0) {
      unsigned int Mx = Mpart[c];
      #pragma unroll
      for (int w = 1; w < 4; ++w) Mx = max(Mx, Mpart[w * NB + c]);
      unsigned int e = Mx >> 23;
      sf = __builtin_bit_cast(float, (254u - e) << 23);
      if (mkc) acc += 127 - (int)e;
    }
    // ---- MFMA: S[tag][batch] = sum_i w[batch][i] * E[i][tag] ----
    f32x4 ac0 = {0.f, 0.f, 0.f, 0.f}, ac1 = {0.f, 0.f, 0.f, 0.f};
    f32x4 ac2 = {0.f, 0.f, 0.f, 0.f}, ac3 = {0.f, 0.f, 0.f, 0.f};
    {
      const unsigned short* rrow = &Wl[t & 1][c * K_];
      #pragma unroll
      for (int kb = 0; kb < 8; ++kb) {
        short8 bf = __builtin_bit_cast(short8,
            *(const uint4*)(&rrow[(kb * 32 + g * 8) ^ swz]));
        ac0 = __builtin_amdgcn_mfma_f32_16x16x32_bf16(Ef[0][kb], bf, ac0, 0, 0, 0);
        ac1 = __builtin_amdgcn_mfma_f32_16x16x32_bf16(Ef[1][kb], bf, ac1, 0, 0, 0);
        ac2 = __builtin_amdgcn_mfma_f32_16x16x32_bf16(Ef[2][kb], bf, ac2, 0, 0, 0);
        ac3 = __builtin_amdgcn_mfma_f32_16x16x32_bf16(Ef[3][kb], bf, ac3, 0, 0, 0);
      }
    }
    // ---- alpha update: a = mask ? ac * (exl*sf) : a ----
    if ((t & 3) == 0) {
      #pragma unroll
      for (int j = 0; j < 16; ++j) exl[j] *= sf;
    }
    {
      #pragma unroll
      for (int i = 0; i < 4; ++i) { float an = ac0[i] * exl[i];      a[i]      = mkc ? an : a[i]; }
      #pragma unroll
      for (int i = 0; i < 4; ++i) { float an = ac1[i] * exl[4 + i];  a[4 + i]  = mkc ? an : a[4 + i]; }
      #pragma unroll
      for (int i = 0; i < 4; ++i) { float an = ac2[i] * exl[8 + i];  a[8 + i]  = mkc ? an : a[8 + i]; }
      #pragma unroll
      for (int i = 0; i < 4; ++i) { float an = ac3[i] * exl[12 + i]; a[12 + i] = mkc ? an : a[12 + i]; }
    }
    // ---- partial max for the next rescale (written at t%4==3) ----
    if ((t & 3) == 3) {
      unsigned int pm = __builtin_bit_cast(uint32_t, a[0]);
      #pragma unroll
      for (int j = 1; j < 16; ++j) pm = max(pm, __builtin_bit_cast(uint32_t, a[j]));
      pm = max(pm, (unsigned int)__shfl_xor((int)pm, 16, 64));
      pm = max(pm, (unsigned int)__shfl_xor((int)pm, 32, 64));
      if (lane < 16) Mpart[wv * NB + c] = pm;
    }
    // ---- exl for t+1 from the arrived prefetch; mask(t+1) ----
    if (t & 1) {
      #pragma unroll
      for (int m = 0; m < 4; ++m) {
        exl[4 * m + 0] = fexp2(xB[m].x * L2E);
        exl[4 * m + 1] = fexp2(xB[m].y * L2E);
        exl[4 * m + 2] = fexp2(xB[m].z * L2E);
        exl[4 * m + 3] = fexp2(xB[m].w * L2E);
      }
    } else {
      #pragma unroll
      for (int m = 0; m < 4; ++m) {
        exl[4 * m + 0] = fexp2(xA[m].x * L2E);
        exl[4 * m + 1] = fexp2(xA[m].y * L2E);
        exl[4 * m + 2] = fexp2(xA[m].z * L2E);
        exl[4 * m + 3] = fexp2(xA[m].w * L2E);
      }
    }
    mkc = mkl[(t + 1 < T_ ? t + 1 : 0) * NB + c];
  }

  // ---- final: out = ln2*(log2(sum alpha) - acc) - score ----
  {
    float ssum = 0.f;
    #pragma unroll
    for (int j = 0; j < 16; ++j) ssum += a[j];
    ssum += __shfl_xor(ssum, 16, 64);
    ssum += __shfl_xor(ssum, 32, 64);
    if (lane < 16) Spart[wv * NB + c] = ssum;
  }
  __syncthreads();
  if (tid < NB) {
    float S = Spart[tid] + Spart[NB + tid] + Spart[2 * NB + tid] + Spart[3 * NB + tid];
    out[b0 + tid] = LN2 * (flog2(S) - (float)acc) - score[b0 + tid];
  }
}

extern "C" void kernel_launch(void* const* d_in, const int* in_sizes, int n_in,
                              void* d_out, int out_size, void* d_ws, size_t ws_size,
                              hipStream_t stream) {
  const float* yp = (const float*)d_in[0];
  const float* trans = (const float*)d_in[1];
  const int* ytrue = (const int*)d_in[2];
  float* out = (float*)d_out;

  unsigned short* Efrag = (unsigned short*)d_ws;                       // 128 KB
  unsigned char* masks = (unsigned char*)d_ws + 131072;                // 64 KB
  float* score = (float*)((char*)d_ws + 131072 + 65536);               // 512 B

  prep_E<<<dim3(256), dim3(256), 0, stream>>>(trans, Efrag);
  aux_mask<<<dim3(16384), dim3(256), 0, stream>>>(yp, masks);
  aux_score<<<dim3(128), dim3(64), 0, stream>>>(yp, trans, ytrue, masks, score);
  crf_scan<<<dim3(8), dim3(256), 0, stream>>>(yp, Efrag, masks, score, out);
}

// Round 4
// 303.714 us; speedup vs baseline: 2.3611x; 2.0328x over previous
//
#include <hip/hip_runtime.h>
#include <stdint.h>

#define T_ 512
#define K_ 256
#define NB 16
#define L2E 1.4426950408889634f
#define LN2 0.6931471805599453f

typedef __attribute__((ext_vector_type(8))) short short8;
typedef __attribute__((ext_vector_type(4))) float f32x4;

__device__ __forceinline__ float fexp2(float x) {
#if __has_builtin(__builtin_amdgcn_exp2f)
  return __builtin_amdgcn_exp2f(x);
#else
  return exp2f(x);
#endif
}
__device__ __forceinline__ float flog2(float x) {
#if __has_builtin(__builtin_amdgcn_logf)
  return __builtin_amdgcn_logf(x);
#else
  return log2f(x);
#endif
}
__device__ __forceinline__ unsigned int umax_(unsigned int a, unsigned int b) {
  return a > b ? a : b;
}
__device__ __forceinline__ unsigned short f2bf(float f) {
  union { float f; uint32_t u; } v; v.f = f;
  uint32_t r = v.u + 0x7fffu + ((v.u >> 16) & 1u);
  return (unsigned short)(r >> 16);
}

// lgkm-only barrier: global loads stay in flight across it
#define BAR() do { \
  asm volatile("s_waitcnt lgkmcnt(0)" ::: "memory"); \
  __builtin_amdgcn_s_barrier(); \
  asm volatile("" ::: "memory"); \
} while (0)

// ---------- aux kernels (byte-identical to round 3, proven) ----------

__global__ void prep_E(const float* __restrict__ trans, unsigned short* __restrict__ Efrag) {
  int idx = blockIdx.x * 256 + threadIdx.x;  // 0..65535
  int e = idx & 7;
  int ln = (idx >> 3) & 63;
  int kb = (idx >> 9) & 7;
  int mt = idx >> 12;
  int j = mt * 16 + (ln & 15);
  int k = kb * 32 + ((ln >> 4) << 3) + e;
  Efrag[idx] = f2bf(__expf(trans[k * K_ + j]));
}

__global__ void aux_mask(const float* __restrict__ yp, unsigned char* __restrict__ masks) {
  int item = blockIdx.x * 4 + (threadIdx.x >> 6);  // b*512 + t
  int lane = threadIdx.x & 63;
  const float4 v = *(const float4*)(yp + (size_t)item * K_ + lane * 4);
  float mn = fminf(fminf(v.x, v.y), fminf(v.z, v.w));
  unsigned long long bl = __ballot(mn > -1000000.0f);
  if (lane == 0) {
    int b = item >> 9, t = item & 511;
    masks[t * 128 + b] = (bl == ~0ull) ? 1 : 0;
  }
}

__global__ void aux_score(const float* __restrict__ yp, const float* __restrict__ trans,
                          const int* __restrict__ ytrue, const unsigned char* __restrict__ masks,
                          float* __restrict__ score) {
  int b = blockIdx.x;
  int lane = threadIdx.x;  // 0..63
  float s = 0.f;
  #pragma unroll
  for (int k = 0; k < 8; ++k) {
    int t = lane + 64 * k;
    int y = ytrue[b * T_ + t];
    int m = masks[t * 128 + b];
    float x = yp[((size_t)b * T_ + t) * K_ + y];
    if (m) s += x;
    if (t >= 1) {
      int ym = ytrue[b * T_ + t - 1];
      int mm = masks[(t - 1) * 128 + b];
      if (m && mm) s += trans[ym * K_ + y];
    }
  }
  #pragma unroll
  for (int off = 32; off; off >>= 1) s += __shfl_xor(s, off, 64);
  if (lane == 0) score[b] = s;
}

// ---------- scan ----------

// One step of the linear-domain recurrence. All loop-variant control is
// template-constant: TM4 = t mod 4 (W parity = TM4&1), RESC at TM4==0,
// MWR (Mpart write) at TM4==3. XN = slot holding x(t+1); XI = slot to
// refill with x(t+4) (slot index t&3, free after exf(t) was built).
template<int TM4, bool RESC, bool MWR, bool MASKED>
__device__ __forceinline__ void crf_step(
    int t, int c, int g, int wv, int swz, const int* tb,
    const short8 (&Ef)[4][8],
    float (&a)[16], float (&exf)[16], int& acc, int& mkc,
    const float* xb, float4 (&XN)[4], float4 (&XI)[4],
    unsigned short (*Wl)[NB * K_], const unsigned char* mkl, unsigned int* Mpart) {
  BAR();
  // rescale (off the MFMA critical path; once per 4 steps)
  if (RESC) {
    unsigned int Mx = Mpart[c];
    Mx = umax_(Mx, Mpart[NB + c]);
    Mx = umax_(Mx, Mpart[2 * NB + c]);
    Mx = umax_(Mx, Mpart[3 * NB + c]);
    unsigned int e_ = Mx >> 23;
    float sf = __builtin_bit_cast(float, (254u - e_) << 23);
    if (!MASKED || mkc) acc += 127 - (int)e_;
    #pragma unroll
    for (int j = 0; j < 16; ++j) exf[j] *= sf;
  }
  // GEMM: S[tag][batch] = sum_i w[batch][i] * E[i][tag]
  f32x4 ac0 = {0.f, 0.f, 0.f, 0.f}, ac1 = {0.f, 0.f, 0.f, 0.f};
  f32x4 ac2 = {0.f, 0.f, 0.f, 0.f}, ac3 = {0.f, 0.f, 0.f, 0.f};
  {
    const unsigned short* rrow = &Wl[TM4 & 1][c * K_];
    #pragma unroll
    for (int kb = 0; kb < 8; ++kb) {
      short8 bf = __builtin_bit_cast(short8,
          *(const uint4*)(&rrow[(kb * 32 + g * 8) ^ swz]));
      ac0 = __builtin_amdgcn_mfma_f32_16x16x32_bf16(Ef[0][kb], bf, ac0, 0, 0, 0);
      ac1 = __builtin_amdgcn_mfma_f32_16x16x32_bf16(Ef[1][kb], bf, ac1, 0, 0, 0);
      ac2 = __builtin_amdgcn_mfma_f32_16x16x32_bf16(Ef[2][kb], bf, ac2, 0, 0, 0);
      ac3 = __builtin_amdgcn_mfma_f32_16x16x32_bf16(Ef[3][kb], bf, ac3, 0, 0, 0);
    }
  }
  // alpha update
  if (MASKED) {
    #pragma unroll
    for (int i = 0; i < 4; ++i) { float an = ac0[i] * exf[i];      a[i]      = mkc ? an : a[i]; }
    #pragma unroll
    for (int i = 0; i < 4; ++i) { float an = ac1[i] * exf[4 + i];  a[4 + i]  = mkc ? an : a[4 + i]; }
    #pragma unroll
    for (int i = 0; i < 4; ++i) { float an = ac2[i] * exf[8 + i];  a[8 + i]  = mkc ? an : a[8 + i]; }
    #pragma unroll
    for (int i = 0; i < 4; ++i) { float an = ac3[i] * exf[12 + i]; a[12 + i] = mkc ? an : a[12 + i]; }
  } else {
    #pragma unroll
    for (int i = 0; i < 4; ++i) a[i]      = ac0[i] * exf[i];
    #pragma unroll
    for (int i = 0; i < 4; ++i) a[4 + i]  = ac1[i] * exf[4 + i];
    #pragma unroll
    for (int i = 0; i < 4; ++i) a[8 + i]  = ac2[i] * exf[8 + i];
    #pragma unroll
    for (int i = 0; i < 4; ++i) a[12 + i] = ac3[i] * exf[12 + i];
  }
  // pack alpha -> bf16 (truncate), write W[(t+1)&1]
  {
    unsigned short* wrow = &Wl[(TM4 + 1) & 1][c * K_];
    #pragma unroll
    for (int m = 0; m < 4; ++m) {
      uint32_t p0 = __builtin_amdgcn_perm(
          __builtin_bit_cast(uint32_t, a[4 * m + 1]),
          __builtin_bit_cast(uint32_t, a[4 * m + 0]), 0x07060302u);
      uint32_t p1 = __builtin_amdgcn_perm(
          __builtin_bit_cast(uint32_t, a[4 * m + 3]),
          __builtin_bit_cast(uint32_t, a[4 * m + 2]), 0x07060302u);
      uint2 pp; pp.x = p0; pp.y = p1;
      *(uint2*)(&wrow[tb[m] ^ swz]) = pp;
    }
  }
  // partial max of alpha for the next rescale
  if (MWR) {
    unsigned int pm = __builtin_bit_cast(uint32_t, a[0]);
    #pragma unroll
    for (int j = 1; j < 16; ++j) pm = umax_(pm, __builtin_bit_cast(uint32_t, a[j]));
    pm = umax_(pm, (unsigned int)__shfl_xor((int)pm, 16, 64));
    pm = umax_(pm, (unsigned int)__shfl_xor((int)pm, 32, 64));
    if (g == 0) Mpart[wv * NB + c] = pm;
  }
  // exf for step t+1 (in MFMA/pack shadow; slot XN loaded >=3 steps ago)
  #pragma unroll
  for (int m = 0; m < 4; ++m) {
    exf[4 * m + 0] = fexp2(XN[m].x * L2E);
    exf[4 * m + 1] = fexp2(XN[m].y * L2E);
    exf[4 * m + 2] = fexp2(XN[m].z * L2E);
    exf[4 * m + 3] = fexp2(XN[m].w * L2E);
  }
  if (MASKED) mkc = mkl[(t + 1 < T_ ? t + 1 : 0) * NB + c];
  // issue x(t+4) into the just-freed slot
  {
    int tt = t + 4;
    tt = tt > (T_ - 1) ? (T_ - 1) : tt;
    #pragma unroll
    for (int m = 0; m < 4; ++m)
      XI[m] = *(const float4*)(xb + (size_t)tt * K_ + tb[m]);
  }
}

template<bool MASKED>
__device__ __forceinline__ void scan_run(
    int tid, int c, int g, int wv, int swz, const int* tb, int b0,
    const short8 (&Ef)[4][8], const float* xb,
    float4 (&xinit)[4], float4 (&X0q)[4], float4 (&X1q)[4],
    float4 (&X2q)[4], float4 (&X3q)[4],
    unsigned short (*Wl)[NB * K_], const unsigned char* mkl,
    unsigned int* Mpart, float* Spart,
    const float* __restrict__ score, float* __restrict__ out) {
  float a[16], exf[16];
  int acc = 0;
  int mkc = 0;
  // alpha(0), linear domain
  {
    int mk0 = MASKED ? mkl[c] : 1;
    #pragma unroll
    for (int m = 0; m < 4; ++m) {
      float e0 = fexp2(xinit[m].x * L2E);
      float e1 = fexp2(xinit[m].y * L2E);
      float e2 = fexp2(xinit[m].z * L2E);
      float e3 = fexp2(xinit[m].w * L2E);
      a[4 * m + 0] = (MASKED && !mk0) ? 1.0f : e0;
      a[4 * m + 1] = (MASKED && !mk0) ? 1.0f : e1;
      a[4 * m + 2] = (MASKED && !mk0) ? 1.0f : e2;
      a[4 * m + 3] = (MASKED && !mk0) ? 1.0f : e3;
    }
  }
  // W[1] <- bf16(alpha(0))  (step t=1 reads parity 1)
  {
    unsigned short* wrow = &Wl[1][c * K_];
    #pragma unroll
    for (int m = 0; m < 4; ++m) {
      uint32_t p0 = __builtin_amdgcn_perm(
          __builtin_bit_cast(uint32_t, a[4 * m + 1]),
          __builtin_bit_cast(uint32_t, a[4 * m + 0]), 0x07060302u);
      uint32_t p1 = __builtin_amdgcn_perm(
          __builtin_bit_cast(uint32_t, a[4 * m + 3]),
          __builtin_bit_cast(uint32_t, a[4 * m + 2]), 0x07060302u);
      uint2 pp; pp.x = p0; pp.y = p1;
      *(uint2*)(&wrow[tb[m] ^ swz]) = pp;
    }
  }
  // exf(1) from X1q; mask(1)
  #pragma unroll
  for (int m = 0; m < 4; ++m) {
    exf[4 * m + 0] = fexp2(X1q[m].x * L2E);
    exf[4 * m + 1] = fexp2(X1q[m].y * L2E);
    exf[4 * m + 2] = fexp2(X1q[m].z * L2E);
    exf[4 * m + 3] = fexp2(X1q[m].w * L2E);
  }
  if (MASKED) mkc = mkl[NB + c];

  // prologue t = 1..3
  crf_step<1, false, false, MASKED>(1, c, g, wv, swz, tb, Ef, a, exf, acc, mkc, xb, X2q, X1q, Wl, mkl, Mpart);
  crf_step<2, false, false, MASKED>(2, c, g, wv, swz, tb, Ef, a, exf, acc, mkc, xb, X3q, X2q, Wl, mkl, Mpart);
  crf_step<3, false, true , MASKED>(3, c, g, wv, swz, tb, Ef, a, exf, acc, mkc, xb, X0q, X3q, Wl, mkl, Mpart);

  #pragma unroll 1
  for (int t0 = 4; t0 < T_; t0 += 4) {
    crf_step<0, true , false, MASKED>(t0,     c, g, wv, swz, tb, Ef, a, exf, acc, mkc, xb, X1q, X0q, Wl, mkl, Mpart);
    crf_step<1, false, false, MASKED>(t0 + 1, c, g, wv, swz, tb, Ef, a, exf, acc, mkc, xb, X2q, X1q, Wl, mkl, Mpart);
    crf_step<2, false, false, MASKED>(t0 + 2, c, g, wv, swz, tb, Ef, a, exf, acc, mkc, xb, X3q, X2q, Wl, mkl, Mpart);
    crf_step<3, false, true , MASKED>(t0 + 3, c, g, wv, swz, tb, Ef, a, exf, acc, mkc, xb, X0q, X3q, Wl, mkl, Mpart);
  }

  // final: out = ln2*(log2(sum alpha) - acc) - score
  __syncthreads();
  {
    float ssum = 0.f;
    #pragma unroll
    for (int j = 0; j < 16; ++j) ssum += a[j];
    ssum += __shfl_xor(ssum, 16, 64);
    ssum += __shfl_xor(ssum, 32, 64);
    if (g == 0) Spart[wv * NB + c] = ssum;
  }
  __syncthreads();
  if (tid < NB) {
    float S = Spart[tid] + Spart[NB + tid] + Spart[2 * NB + tid] + Spart[3 * NB + tid];
    out[b0 + tid] = LN2 * (flog2(S) - (float)acc) - score[b0 + tid];
  }
}

__global__ __launch_bounds__(256, 1) void crf_scan(
    const float* __restrict__ yp, const unsigned short* __restrict__ Efrag,
    const unsigned char* __restrict__ masks, const float* __restrict__ score,
    float* __restrict__ out) {
  const int b0 = blockIdx.x * NB;
  const int tid = threadIdx.x;
  const int wv = tid >> 6, lane = tid & 63;
  const int c = lane & 15;       // batch column
  const int g = lane >> 4;       // k-group / row-group
  const int swz = (c & 7) << 3;  // XOR swizzle in ushort elements (16B granules)

  __shared__ unsigned short Wl[2][NB * K_];  // 16 KB
  __shared__ unsigned char mkl[T_ * NB];     // 8 KB
  __shared__ unsigned int Mpart[4 * NB];
  __shared__ float Spart[4 * NB];
  __shared__ int sflag[4];

  // E fragments -> registers: wave wv owns M-tiles wv*4..wv*4+3
  short8 Ef[4][8];
  {
    const uint4* ep = (const uint4*)Efrag;
    #pragma unroll
    for (int m = 0; m < 4; ++m)
      #pragma unroll
      for (int kb = 0; kb < 8; ++kb)
        Ef[m][kb] = __builtin_bit_cast(short8, ep[((wv * 4 + m) * 8 + kb) * 64 + lane]);
  }

  // mask table -> LDS (mkl[t*16 + c]); also gather all-ones check
  uint4 md0, md1;
  {
    uint4* dst = (uint4*)mkl;
    md0 = *(const uint4*)(masks + (tid)*128 + b0);
    md1 = *(const uint4*)(masks + (tid + 256) * 128 + b0);
    dst[tid] = md0;
    dst[tid + 256] = md1;
  }

  const float* xb = yp + (size_t)(b0 + c) * T_ * K_;
  int tb[4];
  #pragma unroll
  for (int m = 0; m < 4; ++m) tb[m] = wv * 64 + m * 16 + g * 4;

  float4 xinit[4], X0q[4], X1q[4], X2q[4], X3q[4];
  #pragma unroll
  for (int m = 0; m < 4; ++m) xinit[m] = *(const float4*)(xb + tb[m]);
  #pragma unroll
  for (int m = 0; m < 4; ++m) X1q[m] = *(const float4*)(xb + 1 * K_ + tb[m]);
  #pragma unroll
  for (int m = 0; m < 4; ++m) X2q[m] = *(const float4*)(xb + 2 * K_ + tb[m]);
  #pragma unroll
  for (int m = 0; m < 4; ++m) X3q[m] = *(const float4*)(xb + 3 * K_ + tb[m]);
  #pragma unroll
  for (int m = 0; m < 4; ++m) X0q[m] = *(const float4*)(xb + 4 * K_ + tb[m]);

  // all-masks-one check (block-uniform)
  {
    uint32_t w = md0.x & md0.y & md0.z & md0.w & md1.x & md1.y & md1.z & md1.w;
    unsigned long long bl = __ballot(w == 0x01010101u);
    if (lane == 0) sflag[wv] = (bl == ~0ull) ? 1 : 0;
  }
  __syncthreads();
  bool allm = sflag[0] && sflag[1] && sflag[2] && sflag[3];

  if (allm) {
    scan_run<false>(tid, c, g, wv, swz, tb, b0, Ef, xb, xinit, X0q, X1q, X2q, X3q,
                    Wl, mkl, Mpart, Spart, score, out);
  } else {
    scan_run<true>(tid, c, g, wv, swz, tb, b0, Ef, xb, xinit, X0q, X1q, X2q, X3q,
                   Wl, mkl, Mpart, Spart, score, out);
  }
}

extern "C" void kernel_launch(void* const* d_in, const int* in_sizes, int n_in,
                              void* d_out, int out_size, void* d_ws, size_t ws_size,
                              hipStream_t stream) {
  const float* yp = (const float*)d_in[0];
  const float* trans = (const float*)d_in[1];
  const int* ytrue = (const int*)d_in[2];
  float* out = (float*)d_out;

  unsigned short* Efrag = (unsigned short*)d_ws;                 // 128 KB
  unsigned char* masks = (unsigned char*)d_ws + 131072;          // 64 KB
  float* score = (float*)((char*)d_ws + 131072 + 65536);         // 512 B

  prep_E<<<dim3(256), dim3(256), 0, stream>>>(trans, Efrag);
  aux_mask<<<dim3(16384), dim3(256), 0, stream>>>(yp, masks);
  aux_score<<<dim3(128), dim3(64), 0, stream>>>(yp, trans, ytrue, masks, score);
  crf_scan<<<dim3(8), dim3(256), 0, stream>>>(yp, Efrag, masks, score, out);
}